// Round 3
// baseline (226.879 us; speedup 1.0000x reference)
//
#include <hip/hip_runtime.h>
#include <hip/hip_bf16.h>
#include <cstdint>
#include <cstddef>

#define B_ 2
#define S_ 2048
#define D_ 768
#define H_ 12
#define M_ 64
#define BS_ (B_ * S_)

typedef __attribute__((ext_vector_type(8))) short bf16x8;
typedef __attribute__((ext_vector_type(4))) float f32x4;

__device__ __forceinline__ unsigned short f2bu(float f) {
    __hip_bfloat16 h = __float2bfloat16(f);   // RNE
    unsigned short u;
    __builtin_memcpy(&u, &h, 2);
    return u;
}
__device__ __forceinline__ unsigned pack2(float a, float b) {
    return (unsigned)f2bu(a) | ((unsigned)f2bu(b) << 16);
}

// Alias-safe vector load/store (memcpy => char semantics, still b128 ops).
__device__ __forceinline__ bf16x8 ld16(const unsigned short* p) {
    p = (const unsigned short*)__builtin_assume_aligned(p, 16);
    bf16x8 v; __builtin_memcpy(&v, p, 16); return v;
}
__device__ __forceinline__ uint4 ld16u(const unsigned short* p) {
    p = (const unsigned short*)__builtin_assume_aligned(p, 16);
    uint4 v; __builtin_memcpy(&v, p, 16); return v;
}
__device__ __forceinline__ void st16(unsigned short* p, uint4 v) {
    p = (unsigned short*)__builtin_assume_aligned(p, 16);
    __builtin_memcpy(p, &v, 16);
}
__device__ __forceinline__ float4 ldf4(const float* p) {
    p = (const float*)__builtin_assume_aligned(p, 16);
    float4 v; __builtin_memcpy(&v, p, 16); return v;
}

#define NEG_BIG (-3.0e38f)

// ---------------------------------------------------------------------------
// Kernel 1: fused QKV projection (fp32 inputs -> bf16 MFMA -> bf16 ws).
// grid (BS/64, H, 3): 64-row x 64-col (full head) MFMA tile, K-loop over D=768.
// Q output pre-scaled by 1/sqrt(64)=0.125 (applied after bias, fp32).
// Outputs layout [B, H, S, M] so attention reads per-head contiguous matrices.
// ---------------------------------------------------------------------------
__global__ __launch_bounds__(256, 2) void qkv_kernel(
    const float* __restrict__ x,   // [BS, D] fp32
    const float* __restrict__ WQ, const float* __restrict__ bQ,
    const float* __restrict__ WK, const float* __restrict__ bK,
    const float* __restrict__ WV, const float* __restrict__ bV,
    unsigned short* __restrict__ qo, unsigned short* __restrict__ ko,
    unsigned short* __restrict__ vo)
{
    const int h    = blockIdx.y;
    const int row0 = blockIdx.x * 64;
    const int which = blockIdx.z;

    const float* W;
    const float* bias;
    unsigned short* out;
    float scale;
    if (which == 0)      { W = WQ; bias = bQ; out = qo; scale = 0.125f; }
    else if (which == 1) { W = WK; bias = bK; out = ko; scale = 1.0f; }
    else                 { W = WV; bias = bV; out = vo; scale = 1.0f; }
    const float* Wh = W + (size_t)h * D_ * M_;   // row-major [768, 64] fp32

    const int t = threadIdx.x;
    const int wave = t >> 6, lane = t & 63, quad = lane >> 4, l16 = lane & 15;

    __shared__ unsigned short Alds[64][40];   // [row][k] bf16, pad 32->40
    __shared__ unsigned short Wlds[64][40];   // [col][k] transposed bf16

    f32x4 acc[4] = {};

    const float* arow = x + (size_t)(row0 + (t >> 2)) * D_ + (t & 3) * 8;
    const int wcol = t & 63;
    const int wk   = (t >> 6) * 8;

    for (int k0 = 0; k0 < D_; k0 += 32) {
        float4 a0 = ldf4(arow + k0);
        float4 a1 = ldf4(arow + k0 + 4);
        const float* wp = Wh + (size_t)(k0 + wk) * M_ + wcol;
        float wv[8];
#pragma unroll
        for (int i = 0; i < 8; i++) wv[i] = wp[(size_t)i * M_];  // coalesced across lanes

        uint4 av, pu;
        av.x = pack2(a0.x, a0.y); av.y = pack2(a0.z, a0.w);
        av.z = pack2(a1.x, a1.y); av.w = pack2(a1.z, a1.w);
        pu.x = pack2(wv[0], wv[1]); pu.y = pack2(wv[2], wv[3]);
        pu.z = pack2(wv[4], wv[5]); pu.w = pack2(wv[6], wv[7]);

        __syncthreads();
        st16(&Alds[t >> 2][(t & 3) * 8], av);
        st16(&Wlds[wcol][wk], pu);
        __syncthreads();

        bf16x8 af = ld16(&Alds[wave * 16 + l16][quad * 8]);
#pragma unroll
        for (int st = 0; st < 4; st++) {
            bf16x8 bfrag = ld16(&Wlds[st * 16 + l16][quad * 8]);
            acc[st] = __builtin_amdgcn_mfma_f32_16x16x32_bf16(af, bfrag, acc[st], 0, 0, 0);
        }
    }

#pragma unroll
    for (int st = 0; st < 4; st++) {
        const int c = st * 16 + l16;
        const float bval = bias[h * M_ + c];
#pragma unroll
        for (int r = 0; r < 4; r++) {
            const int R  = row0 + wave * 16 + quad * 4 + r;
            const int bb = R >> 11;           // /2048
            const int s  = R & (S_ - 1);
            out[(((size_t)bb * H_ + h) * S_ + s) * M_ + c] =
                f2bu((acc[st][r] + bval) * scale);
        }
    }
}

// ---------------------------------------------------------------------------
// Kernel 2: causal flash attention per (b,h), 64-query tile per block.
// Q pre-scaled. Online softmax in fp32; P -> LDS -> A-layout for PV MFMA.
// z written as [B, S, H*M] (bf16) so the output projection is a plain GEMM.
// ---------------------------------------------------------------------------
__global__ __launch_bounds__(256, 2) void attn_kernel(
    const unsigned short* __restrict__ Q,   // [B,H,S,M] bf16 (scaled)
    const unsigned short* __restrict__ Kin, // [B,H,S,M] bf16
    const unsigned short* __restrict__ Vin, // [B,H,S,M] bf16
    unsigned short* __restrict__ Z)         // [B,S,H*M] bf16
{
    const int qt = blockIdx.x;          // query tile (64 rows)
    const int bh = blockIdx.y;
    const int b = bh / H_, h = bh - b * H_;

    const int t = threadIdx.x;
    const int wave = t >> 6, lane = t & 63, quad = lane >> 4, l16 = lane & 15;

    const unsigned short* Qb = Q   + ((size_t)bh * S_ + qt * 64) * M_;
    const unsigned short* Kb = Kin + (size_t)bh * S_ * M_;
    const unsigned short* Vb = Vin + (size_t)bh * S_ * M_;

    __shared__ unsigned short Klds[64][72];     // [key][feat]
    __shared__ unsigned short Vlds[64][72];     // [feat][key] (transposed)
    __shared__ unsigned short Plds[4][16][72];  // per-wave P strip [q][key]

    // Q fragments: A-layout, rows wave*16+l16, k-chunks 0..31 / 32..63
    bf16x8 qf0, qf1;
    {
        const unsigned short* qrow = Qb + (size_t)(wave * 16 + l16) * M_;
        qf0 = ld16(qrow + quad * 8);
        qf1 = ld16(qrow + 32 + quad * 8);
    }

    f32x4 o_acc[4] = {};
    float mrow[4] = {NEG_BIG, NEG_BIG, NEG_BIG, NEG_BIG};
    float lrow[4] = {0.f, 0.f, 0.f, 0.f};

    for (int kt = 0; kt <= qt; kt++) {
        const unsigned short* kbase = Kb + (size_t)kt * 64 * M_;
        const unsigned short* vbase = Vb + (size_t)kt * 64 * M_;

        // stage K rows (vectorized) and V columns (transposed)
        uint4 kv0 = ld16u(kbase + (size_t)(t >> 2) * M_ + (t & 3) * 16);
        uint4 kv1 = ld16u(kbase + (size_t)(t >> 2) * M_ + (t & 3) * 16 + 8);
        unsigned short vv[16];
#pragma unroll
        for (int i = 0; i < 16; i++)
            vv[i] = vbase[(size_t)((t >> 6) * 16 + i) * M_ + (t & 63)];  // coalesced/lane

        __syncthreads();
        st16(&Klds[t >> 2][(t & 3) * 16], kv0);
        st16(&Klds[t >> 2][(t & 3) * 16 + 8], kv1);
        uint4 v0, v1;
        v0.x = (unsigned)vv[0]  | ((unsigned)vv[1]  << 16);
        v0.y = (unsigned)vv[2]  | ((unsigned)vv[3]  << 16);
        v0.z = (unsigned)vv[4]  | ((unsigned)vv[5]  << 16);
        v0.w = (unsigned)vv[6]  | ((unsigned)vv[7]  << 16);
        v1.x = (unsigned)vv[8]  | ((unsigned)vv[9]  << 16);
        v1.y = (unsigned)vv[10] | ((unsigned)vv[11] << 16);
        v1.z = (unsigned)vv[12] | ((unsigned)vv[13] << 16);
        v1.w = (unsigned)vv[14] | ((unsigned)vv[15] << 16);
        st16(&Vlds[t & 63][(t >> 6) * 16], v0);
        st16(&Vlds[t & 63][(t >> 6) * 16 + 8], v1);
        __syncthreads();

        // S = Q K^T  (already includes 1/8 scale via Q)
        f32x4 s_acc[4];
#pragma unroll
        for (int st = 0; st < 4; st++) {
            f32x4 z4 = {0.f, 0.f, 0.f, 0.f};
            bf16x8 kb0 = ld16(&Klds[st * 16 + l16][quad * 8]);
            bf16x8 kb1 = ld16(&Klds[st * 16 + l16][32 + quad * 8]);
            z4 = __builtin_amdgcn_mfma_f32_16x16x32_bf16(qf0, kb0, z4, 0, 0, 0);
            z4 = __builtin_amdgcn_mfma_f32_16x16x32_bf16(qf1, kb1, z4, 0, 0, 0);
            s_acc[st] = z4;
        }

        // causal mask on the diagonal tile: key > q -> very negative
        if (kt == qt) {
#pragma unroll
            for (int st = 0; st < 4; st++)
#pragma unroll
                for (int r = 0; r < 4; r++)
                    if (st * 16 + l16 > wave * 16 + quad * 4 + r)
                        s_acc[st][r] = -1e30f;
        }

        // row max across the quad's 16 lanes
        float rmax[4];
#pragma unroll
        for (int r = 0; r < 4; r++)
            rmax[r] = fmaxf(fmaxf(s_acc[0][r], s_acc[1][r]),
                            fmaxf(s_acc[2][r], s_acc[3][r]));
#pragma unroll
        for (int off = 1; off < 16; off <<= 1)
#pragma unroll
            for (int r = 0; r < 4; r++)
                rmax[r] = fmaxf(rmax[r], __shfl_xor(rmax[r], off, 64));

        float mnew[4], alpha[4];
#pragma unroll
        for (int r = 0; r < 4; r++) {
            mnew[r]  = fmaxf(mrow[r], rmax[r]);
            alpha[r] = __expf(mrow[r] - mnew[r]);   // first iter: exp(-big)=0
            mrow[r]  = mnew[r];
        }

        // P = exp(S - m), write to LDS (bf16) for layout transform
        float psum[4] = {0.f, 0.f, 0.f, 0.f};
#pragma unroll
        for (int st = 0; st < 4; st++) {
#pragma unroll
            for (int r = 0; r < 4; r++) {
                float p = __expf(s_acc[st][r] - mnew[r]);
                psum[r] += p;
                Plds[wave][quad * 4 + r][st * 16 + l16] = f2bu(p);
            }
        }
#pragma unroll
        for (int off = 1; off < 16; off <<= 1)
#pragma unroll
            for (int r = 0; r < 4; r++)
                psum[r] += __shfl_xor(psum[r], off, 64);

#pragma unroll
        for (int r = 0; r < 4; r++) lrow[r] = lrow[r] * alpha[r] + psum[r];
#pragma unroll
        for (int st = 0; st < 4; st++)
#pragma unroll
            for (int r = 0; r < 4; r++) o_acc[st][r] *= alpha[r];

        // Order the P write->read round-trip for every wave.
        __syncthreads();

        // O += P V  (P re-read in A-layout)
        bf16x8 pf0 = ld16(&Plds[wave][l16][quad * 8]);
        bf16x8 pf1 = ld16(&Plds[wave][l16][32 + quad * 8]);
#pragma unroll
        for (int st = 0; st < 4; st++) {
            bf16x8 vb0 = ld16(&Vlds[st * 16 + l16][quad * 8]);
            bf16x8 vb1 = ld16(&Vlds[st * 16 + l16][32 + quad * 8]);
            o_acc[st] = __builtin_amdgcn_mfma_f32_16x16x32_bf16(pf0, vb0, o_acc[st], 0, 0, 0);
            o_acc[st] = __builtin_amdgcn_mfma_f32_16x16x32_bf16(pf1, vb1, o_acc[st], 0, 0, 0);
        }
    }

    float inv[4];
#pragma unroll
    for (int r = 0; r < 4; r++) inv[r] = 1.0f / lrow[r];
#pragma unroll
    for (int st = 0; st < 4; st++) {
#pragma unroll
        for (int r = 0; r < 4; r++) {
            const int q    = qt * 64 + wave * 16 + quad * 4 + r;
            const int feat = st * 16 + l16;
            Z[((size_t)b * S_ + q) * (H_ * M_) + h * M_ + feat] =
                f2bu(o_acc[st][r] * inv[r]);
        }
    }
}

// ---------------------------------------------------------------------------
// Kernel 3: output projection. attn_out = Z[4096,768](bf16) @ W_O[768,768](fp32)
// + b_O, result fp32. grid (BS/64, D/64), 64x64 MFMA tile.
// ---------------------------------------------------------------------------
__global__ __launch_bounds__(256, 2) void oproj_kernel(
    const unsigned short* __restrict__ Zin,  // [BS, 768] bf16
    const float* __restrict__ WO,            // [768, 768] fp32 (k=h*64+m, d)
    const float* __restrict__ bO,            // [768] fp32
    float* __restrict__ out)                 // [BS, 768] fp32
{
    const int row0 = blockIdx.x * 64;
    const int col0 = blockIdx.y * 64;
    const int t = threadIdx.x;
    const int wave = t >> 6, lane = t & 63, quad = lane >> 4, l16 = lane & 15;

    __shared__ unsigned short Alds[64][40];
    __shared__ unsigned short Wlds[64][40];

    f32x4 acc[4] = {};

    const unsigned short* arow = Zin + (size_t)(row0 + (t >> 2)) * D_ + (t & 3) * 8;
    const int wcol = t & 63;
    const int wk   = (t >> 6) * 8;

    for (int k0 = 0; k0 < D_; k0 += 32) {
        uint4 av = ld16u(arow + k0);
        const float* wp = WO + (size_t)(k0 + wk) * D_ + col0 + wcol;
        float wv[8];
#pragma unroll
        for (int i = 0; i < 8; i++) wv[i] = wp[(size_t)i * D_];

        uint4 pu;
        pu.x = pack2(wv[0], wv[1]); pu.y = pack2(wv[2], wv[3]);
        pu.z = pack2(wv[4], wv[5]); pu.w = pack2(wv[6], wv[7]);

        __syncthreads();
        st16(&Alds[t >> 2][(t & 3) * 8], av);
        st16(&Wlds[wcol][wk], pu);
        __syncthreads();

        bf16x8 af = ld16(&Alds[wave * 16 + l16][quad * 8]);
#pragma unroll
        for (int st = 0; st < 4; st++) {
            bf16x8 bfrag = ld16(&Wlds[st * 16 + l16][quad * 8]);
            acc[st] = __builtin_amdgcn_mfma_f32_16x16x32_bf16(af, bfrag, acc[st], 0, 0, 0);
        }
    }

#pragma unroll
    for (int st = 0; st < 4; st++) {
        const int c = col0 + st * 16 + l16;
        const float bval = bO[c];
#pragma unroll
        for (int r = 0; r < 4; r++) {
            const int R = row0 + wave * 16 + quad * 4 + r;
            out[(size_t)R * D_ + c] = acc[st][r] + bval;
        }
    }
}

// ---------------------------------------------------------------------------
extern "C" void kernel_launch(void* const* d_in, const int* in_sizes, int n_in,
                              void* d_out, int out_size, void* d_ws, size_t ws_size,
                              hipStream_t stream)
{
    const float* x  = (const float*)d_in[0];
    const float* WQ = (const float*)d_in[1];
    const float* bQ = (const float*)d_in[2];
    const float* WK = (const float*)d_in[3];
    const float* bK = (const float*)d_in[4];
    const float* WV = (const float*)d_in[5];
    const float* bV = (const float*)d_in[6];
    const float* WO = (const float*)d_in[7];
    const float* bO = (const float*)d_in[8];
    float* out = (float*)d_out;

    const size_t n = (size_t)B_ * H_ * S_ * M_;   // 3,145,728 elems
    unsigned short* q_ws = (unsigned short*)d_ws;  // [B,H,S,M] bf16, pre-scaled
    unsigned short* k_ws = q_ws + n;
    unsigned short* v_ws = k_ws + n;
    unsigned short* z_ws = v_ws + n;               // [B,S,H*M] bf16

    qkv_kernel<<<dim3(BS_ / 64, H_, 3), 256, 0, stream>>>(
        x, WQ, bQ, WK, bK, WV, bV, q_ws, k_ws, v_ws);
    attn_kernel<<<dim3(S_ / 64, B_ * H_), 256, 0, stream>>>(
        q_ws, k_ws, v_ws, z_ws);
    oproj_kernel<<<dim3(BS_ / 64, D_ / 64), 256, 0, stream>>>(
        z_ws, WO, bO, out);
}